// Round 3
// baseline (5589.020 us; speedup 1.0000x reference)
//
#include <hip/hip_runtime.h>
#include <math.h>

namespace {

constexpr int Bc = 4, Tc = 1024, Cch = 768, Hc = 12, Dc = 64, KSEL = 10;
constexpr size_t BTC    = (size_t)Bc * Tc * Cch;        // 3,145,728
constexpr size_t PROBSN = (size_t)Bc * Hc * Tc * Tc;    // 50,331,648

// ---------------------------------------------------------------------------
// K1: QKV projection.  f32 GEMM, M=4096, N=768, K=768.  Tile 64x128, BK=16.
// ---------------------------------------------------------------------------
__global__ __launch_bounds__(256) void qkv_gemm(
    const float* __restrict__ hid,
    const float* __restrict__ Wq, const float* __restrict__ bq,
    const float* __restrict__ Wk, const float* __restrict__ bk,
    const float* __restrict__ Wv, const float* __restrict__ bv,
    float* __restrict__ qkv)
{
  const int z = blockIdx.z;
  const float* __restrict__ W    = (z == 0) ? Wq : (z == 1) ? Wk : Wv;
  const float* __restrict__ bias = (z == 0) ? bq : (z == 1) ? bk : bv;
  float* __restrict__ out = qkv + (size_t)z * BTC;

  const int m0 = blockIdx.y * 64;
  const int n0 = blockIdx.x * 128;

  __shared__ float aT[16][68];
  __shared__ float bN[16][132];

  const int t  = threadIdx.x;
  const int tn = t & 15;
  const int tq = t >> 4;

  float acc[4][8];
  #pragma unroll
  for (int i = 0; i < 4; ++i)
    #pragma unroll
    for (int j = 0; j < 8; ++j) acc[i][j] = 0.f;

  for (int k0 = 0; k0 < Cch; k0 += 16) {
    __syncthreads();
    {
      const int r = t >> 2, c = t & 3;
      const float4 v = *(const float4*)&hid[(size_t)(m0 + r) * Cch + k0 + 4*c];
      aT[4*c + 0][r] = v.x; aT[4*c + 1][r] = v.y;
      aT[4*c + 2][r] = v.z; aT[4*c + 3][r] = v.w;
    }
    #pragma unroll
    for (int p = 0; p < 2; ++p) {
      const int id = t + 256*p;
      const int kk = id >> 5, nc = id & 31;
      const float4 v = *(const float4*)&W[(size_t)(k0 + kk) * Cch + n0 + 4*nc];
      *(float4*)&bN[kk][4*nc] = v;
    }
    __syncthreads();
    #pragma unroll
    for (int kk = 0; kk < 16; ++kk) {
      const float4 a  = *(const float4*)&aT[kk][4*tq];
      const float4 b0 = *(const float4*)&bN[kk][4*tn];
      const float4 b1 = *(const float4*)&bN[kk][64 + 4*tn];
      const float av[4] = {a.x, a.y, a.z, a.w};
      const float bw[8] = {b0.x, b0.y, b0.z, b0.w, b1.x, b1.y, b1.z, b1.w};
      #pragma unroll
      for (int qi = 0; qi < 4; ++qi)
        #pragma unroll
        for (int ni = 0; ni < 8; ++ni) acc[qi][ni] += av[qi] * bw[ni];
    }
  }

  const float4 bb0 = *(const float4*)&bias[n0 + 4*tn];
  const float4 bb1 = *(const float4*)&bias[n0 + 64 + 4*tn];
  const int h0 = n0 >> 6;
  #pragma unroll
  for (int qi = 0; qi < 4; ++qi) {
    const int m = m0 + 4*tq + qi;
    const int b = m >> 10, tt = m & 1023;
    float4 o0, o1;
    o0.x = acc[qi][0] + bb0.x; o0.y = acc[qi][1] + bb0.y;
    o0.z = acc[qi][2] + bb0.z; o0.w = acc[qi][3] + bb0.w;
    o1.x = acc[qi][4] + bb1.x; o1.y = acc[qi][5] + bb1.y;
    o1.z = acc[qi][6] + bb1.z; o1.w = acc[qi][7] + bb1.w;
    *(float4*)&out[(((size_t)(b*Hc + h0    ))*Tc + tt)*Dc + 4*tn] = o0;
    *(float4*)&out[(((size_t)(b*Hc + h0 + 1))*Tc + tt)*Dc + 4*tn] = o1;
  }
}

// ---------------------------------------------------------------------------
// Phase-3 row processor: softmax + UCB top-k + renorm + count + sparse PV.
// All array indices compile-time static (rule #20).  Called twice explicitly.
// ---------------------------------------------------------------------------
__device__ __forceinline__ void process_row(
    const float (&a)[16], const float (&cnt)[16],
    const int lane, const bool do_ucb, const float lt,
    const size_t rb,
    float* __restrict__ probs_out, float* __restrict__ count_out,
    const float* __restrict__ Vh,      // V base for this (b,h): [1024][64]
    float* __restrict__ ctx_ptr)       // &ctx[row][h*64 + lane]
{
  float s[16];
  #pragma unroll
  for (int w = 0; w < 16; ++w) s[w] = a[w] * 0.125f;   // /sqrt(64)

  float mx = -INFINITY;
  #pragma unroll
  for (int w = 0; w < 16; ++w) mx = fmaxf(mx, s[w]);
  #pragma unroll
  for (int off = 32; off > 0; off >>= 1) mx = fmaxf(mx, __shfl_xor(mx, off));

  float sum = 0.f;
  #pragma unroll
  for (int w = 0; w < 16; ++w) { s[w] = expf(s[w] - mx); sum += s[w]; }
  #pragma unroll
  for (int off = 32; off > 0; off >>= 1) sum += __shfl_xor(sum, off);

  #pragma unroll
  for (int w = 0; w < 16; ++w) s[w] = s[w] / sum;      // att (same as ref)

  if (do_ucb) {
    float u[16];
    #pragma unroll
    for (int w = 0; w < 16; ++w)
      u[w] = s[w] + sqrtf(lt / (cnt[w] + 1e-8f));

    float pvv[KSEL];
    int   kvv[KSEL];
    unsigned sel = 0u;
    #pragma unroll
    for (int r = 0; r < KSEL; ++r) {
      float bu = -INFINITY, bs = 0.f; int bk = 1 << 30;
      #pragma unroll
      for (int w = 0; w < 16; ++w) {
        if (!((sel >> w) & 1u)) {
          const int kk = lane + 64*w;
          if (u[w] > bu || (u[w] == bu && kk < bk)) {
            bu = u[w]; bs = s[w]; bk = kk;
          }
        }
      }
      #pragma unroll
      for (int off = 32; off > 0; off >>= 1) {
        const float ov = __shfl_xor(bu, off);
        const float os = __shfl_xor(bs, off);
        const int   ok = __shfl_xor(bk, off);
        if (ov > bu || (ov == bu && ok < bk)) { bu = ov; bs = os; bk = ok; }
      }
      if ((bk & 63) == lane) sel |= 1u << (bk >> 6);
      pvv[r] = bs; kvv[r] = bk;
    }

    float denom = 1e-8f;
    #pragma unroll
    for (int r = 0; r < KSEL; ++r) denom += pvv[r];
    const float rden = 1.0f / denom;

    #pragma unroll
    for (int w = 0; w < 16; ++w) {
      const bool sb = (sel >> w) & 1u;
      probs_out[rb + lane + 64*w] = sb ? (s[w] * rden) : 0.0f;
      count_out[rb + lane + 64*w] = cnt[w] + (sb ? 1.0f : 0.0f);
    }

    // sparse PV: ctx[d=lane] = (sum_r pvv[r] * V[kvv[r]][d]) * rden
    float cd = 0.f;
    #pragma unroll
    for (int r = 0; r < KSEL; ++r)
      cd += pvv[r] * Vh[(size_t)kvv[r] * Dc + lane];
    *ctx_ptr = cd * rden;
  } else {
    #pragma unroll
    for (int w = 0; w < 16; ++w) {
      probs_out[rb + lane + 64*w] = s[w];
      count_out[rb + lane + 64*w] = cnt[w];
    }
    // dense ctx handled by guarded pv_gemm fallback
  }
}

// ---------------------------------------------------------------------------
// K2: fused scores + softmax + UCB top-k + renorm + count + sparse PV.
// 512 threads (8 waves), 16 q-rows/block; wave w owns rows 2w,2w+1; lane owns
// k = lane + 64*w16.  Chunk loop FULLY UNROLLED so acc0/acc1 stay in VGPRs;
// K tile register-prefetched (issue-early / commit-late).
// ---------------------------------------------------------------------------
__global__ __launch_bounds__(512) void attn_ucb(
    const float* __restrict__ qkv,
    const float* __restrict__ count_in,
    const int*   __restrict__ counter_p,
    const int*   __restrict__ ucb_p,
    float* __restrict__ probs_out,
    float* __restrict__ count_out,
    float* __restrict__ ctx)
{
  const int bh = blockIdx.y;
  const int q0 = blockIdx.x * 16;
  const int b  = bh / Hc, h = bh % Hc;
  const float* __restrict__ Qm = qkv;
  const float* __restrict__ Km = qkv + BTC;
  const float* __restrict__ Vh = qkv + 2*BTC + (size_t)bh * Tc * Dc;

  __shared__ float kN[128][68];
  __shared__ float qN[16][68];

  const int t    = threadIdx.x;
  const int lane = t & 63;
  const int wv   = t >> 6;

  if (t < 256) {   // stage Q tile 16x64
    const int dq = t & 15, r = t >> 4;
    const float4 v = *(const float4*)&Qm[((size_t)bh*Tc + q0 + r)*Dc + 4*dq];
    *(float4*)&qN[r][4*dq] = v;
  }

  const int    dc    = t & 15;
  const int    kr    = t >> 4;
  const size_t kbase = (size_t)bh * Tc * Dc;

  float4 st[4];
  auto issue = [&](int j) {
    #pragma unroll
    for (int p = 0; p < 4; ++p)
      st[p] = *(const float4*)&Km[kbase + (size_t)(128*j + kr + 32*p)*Dc + 4*dc];
  };
  auto commit = [&]() {
    #pragma unroll
    for (int p = 0; p < 4; ++p)
      *(float4*)&kN[kr + 32*p][4*dc] = st[p];
  };

  float acc0[16], acc1[16];
  #pragma unroll
  for (int w = 0; w < 16; ++w) { acc0[w] = 0.f; acc1[w] = 0.f; }

  issue(0); commit();
  __syncthreads();

  #pragma unroll
  for (int j = 0; j < 8; ++j) {          // fully unrolled -> static acc idx
    if (j < 7) issue(j + 1);             // loads in flight during compute
    #pragma unroll
    for (int d4 = 0; d4 < 16; ++d4) {
      const float4 qa = *(const float4*)&qN[2*wv    ][4*d4];
      const float4 qb = *(const float4*)&qN[2*wv + 1][4*d4];
      #pragma unroll
      for (int c = 0; c < 2; ++c) {
        const float4 kv4 = *(const float4*)&kN[lane + 64*c][4*d4];
        acc0[2*j + c] += qa.x*kv4.x + qa.y*kv4.y + qa.z*kv4.z + qa.w*kv4.w;
        acc1[2*j + c] += qb.x*kv4.x + qb.y*kv4.y + qb.z*kv4.z + qb.w*kv4.w;
      }
    }
    __syncthreads();
    if (j < 7) { commit(); __syncthreads(); }
  }

  // ---- phase 3 ----
  const int  counter = counter_p[0];
  const int  ucbf    = ucb_p[0];
  const bool do_ucb  = (ucbf != 0) && (counter >= 1000);
  const float lt     = do_ucb ? logf((float)counter) : 0.f;

  const int    row0 = q0 + 2*wv;
  const int    row1 = row0 + 1;
  const size_t rb0  = ((size_t)bh*Tc + row0) * Tc;
  const size_t rb1  = ((size_t)bh*Tc + row1) * Tc;

  float cnt0[16], cnt1[16];
  #pragma unroll
  for (int w = 0; w < 16; ++w) cnt0[w] = count_in[rb0 + lane + 64*w];
  #pragma unroll
  for (int w = 0; w < 16; ++w) cnt1[w] = count_in[rb1 + lane + 64*w];

  float* ctx0 = &ctx[((size_t)b*Tc + row0)*Cch + h*Dc + lane];
  float* ctx1 = &ctx[((size_t)b*Tc + row1)*Cch + h*Dc + lane];

  process_row(acc0, cnt0, lane, do_ucb, lt, rb0, probs_out, count_out, Vh, ctx0);
  process_row(acc1, cnt1, lane, do_ucb, lt, rb1, probs_out, count_out, Vh, ctx1);
}

// ---------------------------------------------------------------------------
// K3 (fallback only, non-UCB path): ctx = probs @ V per (b,h).
// Early-exits on device when the UCB path already produced ctx in K2.
// ---------------------------------------------------------------------------
__global__ __launch_bounds__(256) void pv_gemm(
    const float* __restrict__ probs,
    const float* __restrict__ Vm,
    float* __restrict__ ctx,
    const int* __restrict__ counter_p,
    const int* __restrict__ ucb_p)
{
  if ((ucb_p[0] != 0) && (counter_p[0] >= 1000)) return;  // K2 did sparse PV

  const int bh = blockIdx.y;
  const int q0 = blockIdx.x * 64;
  const int b = bh / Hc, h = bh % Hc;

  __shared__ float aT[32][68];
  __shared__ float vN[32][68];

  const int t  = threadIdx.x;
  const int tn = t & 15;
  const int tq = t >> 4;

  float acc[4][4];
  #pragma unroll
  for (int i = 0; i < 4; ++i)
    #pragma unroll
    for (int j = 0; j < 4; ++j) acc[i][j] = 0.f;

  for (int k0 = 0; k0 < Tc; k0 += 32) {
    __syncthreads();
    #pragma unroll
    for (int p = 0; p < 2; ++p) {
      const int id = t + 256*p;
      const int r = id >> 3, c = id & 7;
      const float4 v =
          *(const float4*)&probs[((size_t)bh*Tc + q0 + r)*Tc + k0 + 4*c];
      aT[4*c + 0][r] = v.x; aT[4*c + 1][r] = v.y;
      aT[4*c + 2][r] = v.z; aT[4*c + 3][r] = v.w;
    }
    #pragma unroll
    for (int p = 0; p < 2; ++p) {
      const int id = t + 256*p;
      const int kk = id >> 4, dcc = id & 15;
      const float4 v = *(const float4*)&Vm[((size_t)bh*Tc + k0 + kk)*Dc + 4*dcc];
      *(float4*)&vN[kk][4*dcc] = v;
    }
    __syncthreads();
    #pragma unroll
    for (int kk = 0; kk < 32; ++kk) {
      const float4 a  = *(const float4*)&aT[kk][4*tq];
      const float4 vv = *(const float4*)&vN[kk][4*tn];
      const float av[4] = {a.x, a.y, a.z, a.w};
      const float bw[4] = {vv.x, vv.y, vv.z, vv.w};
      #pragma unroll
      for (int qi = 0; qi < 4; ++qi)
        #pragma unroll
        for (int ni = 0; ni < 4; ++ni) acc[qi][ni] += av[qi] * bw[ni];
    }
  }

  #pragma unroll
  for (int qi = 0; qi < 4; ++qi) {
    const int tt = q0 + 4*tq + qi;
    float4 o;
    o.x = acc[qi][0]; o.y = acc[qi][1]; o.z = acc[qi][2]; o.w = acc[qi][3];
    *(float4*)&ctx[((size_t)b*Tc + tt)*Cch + h*Dc + 4*tn] = o;
  }
}

// ---------------------------------------------------------------------------
// K4: out = ctx @ Wo + bo.
// ---------------------------------------------------------------------------
__global__ __launch_bounds__(256) void out_gemm(
    const float* __restrict__ A,
    const float* __restrict__ W,
    const float* __restrict__ bias,
    float* __restrict__ out)
{
  const int m0 = blockIdx.y * 64;
  const int n0 = blockIdx.x * 128;

  __shared__ float aT[16][68];
  __shared__ float bN[16][132];

  const int t  = threadIdx.x;
  const int tn = t & 15;
  const int tq = t >> 4;

  float acc[4][8];
  #pragma unroll
  for (int i = 0; i < 4; ++i)
    #pragma unroll
    for (int j = 0; j < 8; ++j) acc[i][j] = 0.f;

  for (int k0 = 0; k0 < Cch; k0 += 16) {
    __syncthreads();
    {
      const int r = t >> 2, c = t & 3;
      const float4 v = *(const float4*)&A[(size_t)(m0 + r) * Cch + k0 + 4*c];
      aT[4*c + 0][r] = v.x; aT[4*c + 1][r] = v.y;
      aT[4*c + 2][r] = v.z; aT[4*c + 3][r] = v.w;
    }
    #pragma unroll
    for (int p = 0; p < 2; ++p) {
      const int id = t + 256*p;
      const int kk = id >> 5, nc = id & 31;
      const float4 v = *(const float4*)&W[(size_t)(k0 + kk) * Cch + n0 + 4*nc];
      *(float4*)&bN[kk][4*nc] = v;
    }
    __syncthreads();
    #pragma unroll
    for (int kk = 0; kk < 16; ++kk) {
      const float4 a  = *(const float4*)&aT[kk][4*tq];
      const float4 b0 = *(const float4*)&bN[kk][4*tn];
      const float4 b1 = *(const float4*)&bN[kk][64 + 4*tn];
      const float av[4] = {a.x, a.y, a.z, a.w};
      const float bw[8] = {b0.x, b0.y, b0.z, b0.w, b1.x, b1.y, b1.z, b1.w};
      #pragma unroll
      for (int qi = 0; qi < 4; ++qi)
        #pragma unroll
        for (int ni = 0; ni < 8; ++ni) acc[qi][ni] += av[qi] * bw[ni];
    }
  }

  const float4 bb0 = *(const float4*)&bias[n0 + 4*tn];
  const float4 bb1 = *(const float4*)&bias[n0 + 64 + 4*tn];
  #pragma unroll
  for (int qi = 0; qi < 4; ++qi) {
    const int m = m0 + 4*tq + qi;
    float4 o0, o1;
    o0.x = acc[qi][0] + bb0.x; o0.y = acc[qi][1] + bb0.y;
    o0.z = acc[qi][2] + bb0.z; o0.w = acc[qi][3] + bb0.w;
    o1.x = acc[qi][4] + bb1.x; o1.y = acc[qi][5] + bb1.y;
    o1.z = acc[qi][6] + bb1.z; o1.w = acc[qi][7] + bb1.w;
    *(float4*)&out[(size_t)m * Cch + n0 + 4*tn]      = o0;
    *(float4*)&out[(size_t)m * Cch + n0 + 64 + 4*tn] = o1;
  }
}

} // anonymous namespace

// ---------------------------------------------------------------------------
extern "C" void kernel_launch(void* const* d_in, const int* in_sizes, int n_in,
                              void* d_out, int out_size, void* d_ws, size_t ws_size,
                              hipStream_t stream) {
  (void)in_sizes; (void)n_in; (void)out_size; (void)ws_size;

  const float* hid  = (const float*)d_in[0];
  const float* cnt  = (const float*)d_in[1];
  const float* Wq   = (const float*)d_in[2];
  const float* bq   = (const float*)d_in[3];
  const float* Wk   = (const float*)d_in[4];
  const float* bk   = (const float*)d_in[5];
  const float* Wv   = (const float*)d_in[6];
  const float* bv   = (const float*)d_in[7];
  const float* Wo   = (const float*)d_in[8];
  const float* bo   = (const float*)d_in[9];
  const int* counter = (const int*)d_in[10];
  const int* ucb     = (const int*)d_in[11];

  float* out       = (float*)d_out;          // [B,T,C]
  float* probs     = out + BTC;              // [B,H,T,T]
  float* count_out = probs + PROBSN;         // [B,H,T,T]

  // workspace: Q | K | V | ctx, each BTC floats (needs 50.3 MB)
  float* ws  = (float*)d_ws;
  float* ctx = ws + 3*BTC;

  qkv_gemm<<<dim3(Cch/128, (Bc*Tc)/64, 3), 256, 0, stream>>>(
      hid, Wq, bq, Wk, bk, Wv, bv, ws);

  attn_ucb<<<dim3(Tc/16, Bc*Hc), 512, 0, stream>>>(
      ws, cnt, counter, ucb, probs, count_out, ctx);

  pv_gemm<<<dim3(Tc/64, Bc*Hc), 256, 0, stream>>>(
      probs, ws + 2*BTC, ctx, counter, ucb);

  out_gemm<<<dim3(Cch/128, (Bc*Tc)/64), 256, 0, stream>>>(
      ctx, Wo, bo, out);
}

// Round 4
// 5083.380 us; speedup vs baseline: 1.0995x; 1.0995x over previous
//
#include <hip/hip_runtime.h>
#include <math.h>

namespace {

constexpr int Bc = 4, Tc = 1024, Cch = 768, Hc = 12, Dc = 64, KSEL = 10;
constexpr size_t BTC    = (size_t)Bc * Tc * Cch;        // 3,145,728
constexpr size_t PROBSN = (size_t)Bc * Hc * Tc * Tc;    // 50,331,648

// ---------------------------------------------------------------------------
// K1: QKV projection.  f32 GEMM, M=4096, N=768, K=768.  Tile 64x128, BK=16.
// ---------------------------------------------------------------------------
__global__ __launch_bounds__(256) void qkv_gemm(
    const float* __restrict__ hid,
    const float* __restrict__ Wq, const float* __restrict__ bq,
    const float* __restrict__ Wk, const float* __restrict__ bk,
    const float* __restrict__ Wv, const float* __restrict__ bv,
    float* __restrict__ qkv)
{
  const int z = blockIdx.z;
  const float* __restrict__ W    = (z == 0) ? Wq : (z == 1) ? Wk : Wv;
  const float* __restrict__ bias = (z == 0) ? bq : (z == 1) ? bk : bv;
  float* __restrict__ out = qkv + (size_t)z * BTC;

  const int m0 = blockIdx.y * 64;
  const int n0 = blockIdx.x * 128;

  __shared__ float aT[16][68];
  __shared__ float bN[16][132];

  const int t  = threadIdx.x;
  const int tn = t & 15;
  const int tq = t >> 4;

  float acc[4][8];
  #pragma unroll
  for (int i = 0; i < 4; ++i)
    #pragma unroll
    for (int j = 0; j < 8; ++j) acc[i][j] = 0.f;

  for (int k0 = 0; k0 < Cch; k0 += 16) {
    __syncthreads();
    {
      const int r = t >> 2, c = t & 3;
      const float4 v = *(const float4*)&hid[(size_t)(m0 + r) * Cch + k0 + 4*c];
      aT[4*c + 0][r] = v.x; aT[4*c + 1][r] = v.y;
      aT[4*c + 2][r] = v.z; aT[4*c + 3][r] = v.w;
    }
    #pragma unroll
    for (int p = 0; p < 2; ++p) {
      const int id = t + 256*p;
      const int kk = id >> 5, nc = id & 31;
      const float4 v = *(const float4*)&W[(size_t)(k0 + kk) * Cch + n0 + 4*nc];
      *(float4*)&bN[kk][4*nc] = v;
    }
    __syncthreads();
    #pragma unroll
    for (int kk = 0; kk < 16; ++kk) {
      const float4 a  = *(const float4*)&aT[kk][4*tq];
      const float4 b0 = *(const float4*)&bN[kk][4*tn];
      const float4 b1 = *(const float4*)&bN[kk][64 + 4*tn];
      const float av[4] = {a.x, a.y, a.z, a.w};
      const float bw[8] = {b0.x, b0.y, b0.z, b0.w, b1.x, b1.y, b1.z, b1.w};
      #pragma unroll
      for (int qi = 0; qi < 4; ++qi)
        #pragma unroll
        for (int ni = 0; ni < 8; ++ni) acc[qi][ni] += av[qi] * bw[ni];
    }
  }

  const float4 bb0 = *(const float4*)&bias[n0 + 4*tn];
  const float4 bb1 = *(const float4*)&bias[n0 + 64 + 4*tn];
  const int h0 = n0 >> 6;
  #pragma unroll
  for (int qi = 0; qi < 4; ++qi) {
    const int m = m0 + 4*tq + qi;
    const int b = m >> 10, tt = m & 1023;
    float4 o0, o1;
    o0.x = acc[qi][0] + bb0.x; o0.y = acc[qi][1] + bb0.y;
    o0.z = acc[qi][2] + bb0.z; o0.w = acc[qi][3] + bb0.w;
    o1.x = acc[qi][4] + bb1.x; o1.y = acc[qi][5] + bb1.y;
    o1.z = acc[qi][6] + bb1.z; o1.w = acc[qi][7] + bb1.w;
    *(float4*)&out[(((size_t)(b*Hc + h0    ))*Tc + tt)*Dc + 4*tn] = o0;
    *(float4*)&out[(((size_t)(b*Hc + h0 + 1))*Tc + tt)*Dc + 4*tn] = o1;
  }
}

// ---------------------------------------------------------------------------
// Phase-3 row processor: softmax + UCB top-k + renorm + count + sparse PV.
// Register discipline: cnt is STREAMED (loaded into u, re-read at write time
// from L2) so only s[16]+u[16]+pvv[10]+kvv[10] are live at peak.
// ---------------------------------------------------------------------------
__device__ __forceinline__ void process_row(
    const float (&a)[16],
    const int lane, const bool do_ucb, const float lt,
    const size_t rb,
    const float* __restrict__ count_in,
    float* __restrict__ probs_out, float* __restrict__ count_out,
    const float* __restrict__ Vh,      // V base for this (b,h): [1024][64]
    float* __restrict__ ctx_ptr)       // &ctx[row][h*64 + lane]
{
  float s[16];
  #pragma unroll
  for (int w = 0; w < 16; ++w) s[w] = a[w] * 0.125f;   // /sqrt(64)

  float mx = -INFINITY;
  #pragma unroll
  for (int w = 0; w < 16; ++w) mx = fmaxf(mx, s[w]);
  #pragma unroll
  for (int off = 32; off > 0; off >>= 1) mx = fmaxf(mx, __shfl_xor(mx, off));

  float sum = 0.f;
  #pragma unroll
  for (int w = 0; w < 16; ++w) { s[w] = __expf(s[w] - mx); sum += s[w]; }
  #pragma unroll
  for (int off = 32; off > 0; off >>= 1) sum += __shfl_xor(sum, off);

  const float rsum = 1.0f / sum;
  #pragma unroll
  for (int w = 0; w < 16; ++w) s[w] = s[w] * rsum;     // att

  if (do_ucb) {
    float u[16];
    #pragma unroll
    for (int w = 0; w < 16; ++w) {
      const float c = count_in[rb + lane + 64*w];      // streamed, not kept
      u[w] = s[w] + sqrtf(lt / (c + 1e-8f));
    }

    float pvv[KSEL];
    int   kvv[KSEL];
    unsigned sel = 0u;
    #pragma unroll
    for (int r = 0; r < KSEL; ++r) {
      float bu = -INFINITY, bs = 0.f; int bk = 1 << 30;
      #pragma unroll
      for (int w = 0; w < 16; ++w) {
        if (!((sel >> w) & 1u)) {
          const int kk = lane + 64*w;
          if (u[w] > bu || (u[w] == bu && kk < bk)) {
            bu = u[w]; bs = s[w]; bk = kk;
          }
        }
      }
      #pragma unroll
      for (int off = 32; off > 0; off >>= 1) {
        const float ov = __shfl_xor(bu, off);
        const float os = __shfl_xor(bs, off);
        const int   ok = __shfl_xor(bk, off);
        if (ov > bu || (ov == bu && ok < bk)) { bu = ov; bs = os; bk = ok; }
      }
      if ((bk & 63) == lane) sel |= 1u << (bk >> 6);
      pvv[r] = bs; kvv[r] = bk;
    }
    // u dead from here on

    float denom = 1e-8f;
    #pragma unroll
    for (int r = 0; r < KSEL; ++r) denom += pvv[r];
    const float rden = 1.0f / denom;

    #pragma unroll
    for (int w = 0; w < 16; ++w) {
      const float c  = count_in[rb + lane + 64*w];     // L2-hot re-read
      const bool  sb = (sel >> w) & 1u;
      probs_out[rb + lane + 64*w] = sb ? (s[w] * rden) : 0.0f;
      count_out[rb + lane + 64*w] = c + (sb ? 1.0f : 0.0f);
    }

    // sparse PV: ctx[d=lane] = (sum_r pvv[r] * V[kvv[r]][d]) * rden
    float cd = 0.f;
    #pragma unroll
    for (int r = 0; r < KSEL; ++r)
      cd += pvv[r] * Vh[(size_t)kvv[r] * Dc + lane];
    *ctx_ptr = cd * rden;
  } else {
    #pragma unroll
    for (int w = 0; w < 16; ++w) {
      probs_out[rb + lane + 64*w] = s[w];
      count_out[rb + lane + 64*w] = count_in[rb + lane + 64*w];
    }
    // dense ctx handled by guarded pv_gemm fallback
  }
}

// ---------------------------------------------------------------------------
// K2: fused scores + softmax + UCB top-k + renorm + count + sparse PV.
// 512 threads (8 waves), 16 q-rows/block; wave w owns rows 2w,2w+1; lane owns
// k = lane + 64*w16.  Chunk loop fully unrolled (static acc idx); K tile
// register-prefetched.  __launch_bounds__(512,2): VGPR ceiling 256, no spill.
// ---------------------------------------------------------------------------
__global__ __launch_bounds__(512, 2) void attn_ucb(
    const float* __restrict__ qkv,
    const float* __restrict__ count_in,
    const int*   __restrict__ counter_p,
    const int*   __restrict__ ucb_p,
    float* __restrict__ probs_out,
    float* __restrict__ count_out,
    float* __restrict__ ctx)
{
  const int bh = blockIdx.y;
  const int q0 = blockIdx.x * 16;
  const int b  = bh / Hc, h = bh % Hc;
  const float* __restrict__ Qm = qkv;
  const float* __restrict__ Km = qkv + BTC;
  const float* __restrict__ Vh = qkv + 2*BTC + (size_t)bh * Tc * Dc;

  __shared__ float kN[128][68];
  __shared__ float qN[16][68];

  const int t    = threadIdx.x;
  const int lane = t & 63;
  const int wv   = t >> 6;

  if (t < 256) {   // stage Q tile 16x64
    const int dq = t & 15, r = t >> 4;
    const float4 v = *(const float4*)&Qm[((size_t)bh*Tc + q0 + r)*Dc + 4*dq];
    *(float4*)&qN[r][4*dq] = v;
  }

  const int    dc    = t & 15;
  const int    kr    = t >> 4;
  const size_t kbase = (size_t)bh * Tc * Dc;

  float4 st[4];
  auto issue = [&](int j) {
    #pragma unroll
    for (int p = 0; p < 4; ++p)
      st[p] = *(const float4*)&Km[kbase + (size_t)(128*j + kr + 32*p)*Dc + 4*dc];
  };
  auto commit = [&]() {
    #pragma unroll
    for (int p = 0; p < 4; ++p)
      *(float4*)&kN[kr + 32*p][4*dc] = st[p];
  };

  float acc0[16], acc1[16];
  #pragma unroll
  for (int w = 0; w < 16; ++w) { acc0[w] = 0.f; acc1[w] = 0.f; }

  issue(0); commit();
  __syncthreads();

  #pragma unroll
  for (int j = 0; j < 8; ++j) {          // fully unrolled -> static acc idx
    if (j < 7) issue(j + 1);             // loads in flight during compute
    #pragma unroll
    for (int d4 = 0; d4 < 16; ++d4) {
      const float4 qa = *(const float4*)&qN[2*wv    ][4*d4];
      const float4 qb = *(const float4*)&qN[2*wv + 1][4*d4];
      #pragma unroll
      for (int c = 0; c < 2; ++c) {
        const float4 kv4 = *(const float4*)&kN[lane + 64*c][4*d4];
        acc0[2*j + c] += qa.x*kv4.x + qa.y*kv4.y + qa.z*kv4.z + qa.w*kv4.w;
        acc1[2*j + c] += qb.x*kv4.x + qb.y*kv4.y + qb.z*kv4.z + qb.w*kv4.w;
      }
    }
    __syncthreads();
    if (j < 7) { commit(); __syncthreads(); }
  }

  // ---- phase 3 ----
  const int  counter = counter_p[0];
  const int  ucbf    = ucb_p[0];
  const bool do_ucb  = (ucbf != 0) && (counter >= 1000);
  const float lt     = do_ucb ? logf((float)counter) : 0.f;

  const int    row0 = q0 + 2*wv;
  const int    row1 = row0 + 1;
  const size_t rb0  = ((size_t)bh*Tc + row0) * Tc;
  const size_t rb1  = ((size_t)bh*Tc + row1) * Tc;

  float* ctx0 = &ctx[((size_t)b*Tc + row0)*Cch + h*Dc + lane];
  float* ctx1 = &ctx[((size_t)b*Tc + row1)*Cch + h*Dc + lane];

  process_row(acc0, lane, do_ucb, lt, rb0, count_in,
              probs_out, count_out, Vh, ctx0);
  process_row(acc1, lane, do_ucb, lt, rb1, count_in,
              probs_out, count_out, Vh, ctx1);
}

// ---------------------------------------------------------------------------
// K3 (fallback only, non-UCB path): ctx = probs @ V per (b,h).
// ---------------------------------------------------------------------------
__global__ __launch_bounds__(256) void pv_gemm(
    const float* __restrict__ probs,
    const float* __restrict__ Vm,
    float* __restrict__ ctx,
    const int* __restrict__ counter_p,
    const int* __restrict__ ucb_p)
{
  if ((ucb_p[0] != 0) && (counter_p[0] >= 1000)) return;  // K2 did sparse PV

  const int bh = blockIdx.y;
  const int q0 = blockIdx.x * 64;
  const int b = bh / Hc, h = bh % Hc;

  __shared__ float aT[32][68];
  __shared__ float vN[32][68];

  const int t  = threadIdx.x;
  const int tn = t & 15;
  const int tq = t >> 4;

  float acc[4][4];
  #pragma unroll
  for (int i = 0; i < 4; ++i)
    #pragma unroll
    for (int j = 0; j < 4; ++j) acc[i][j] = 0.f;

  for (int k0 = 0; k0 < Tc; k0 += 32) {
    __syncthreads();
    #pragma unroll
    for (int p = 0; p < 2; ++p) {
      const int id = t + 256*p;
      const int r = id >> 3, c = id & 7;
      const float4 v =
          *(const float4*)&probs[((size_t)bh*Tc + q0 + r)*Tc + k0 + 4*c];
      aT[4*c + 0][r] = v.x; aT[4*c + 1][r] = v.y;
      aT[4*c + 2][r] = v.z; aT[4*c + 3][r] = v.w;
    }
    #pragma unroll
    for (int p = 0; p < 2; ++p) {
      const int id = t + 256*p;
      const int kk = id >> 4, dcc = id & 15;
      const float4 v = *(const float4*)&Vm[((size_t)bh*Tc + k0 + kk)*Dc + 4*dcc];
      *(float4*)&vN[kk][4*dcc] = v;
    }
    __syncthreads();
    #pragma unroll
    for (int kk = 0; kk < 32; ++kk) {
      const float4 a  = *(const float4*)&aT[kk][4*tq];
      const float4 vv = *(const float4*)&vN[kk][4*tn];
      const float av[4] = {a.x, a.y, a.z, a.w};
      const float bw[4] = {vv.x, vv.y, vv.z, vv.w};
      #pragma unroll
      for (int qi = 0; qi < 4; ++qi)
        #pragma unroll
        for (int ni = 0; ni < 4; ++ni) acc[qi][ni] += av[qi] * bw[ni];
    }
  }

  #pragma unroll
  for (int qi = 0; qi < 4; ++qi) {
    const int tt = q0 + 4*tq + qi;
    float4 o;
    o.x = acc[qi][0]; o.y = acc[qi][1]; o.z = acc[qi][2]; o.w = acc[qi][3];
    *(float4*)&ctx[((size_t)b*Tc + tt)*Cch + h*Dc + 4*tn] = o;
  }
}

// ---------------------------------------------------------------------------
// K4: out = ctx @ Wo + bo.
// ---------------------------------------------------------------------------
__global__ __launch_bounds__(256) void out_gemm(
    const float* __restrict__ A,
    const float* __restrict__ W,
    const float* __restrict__ bias,
    float* __restrict__ out)
{
  const int m0 = blockIdx.y * 64;
  const int n0 = blockIdx.x * 128;

  __shared__ float aT[16][68];
  __shared__ float bN[16][132];

  const int t  = threadIdx.x;
  const int tn = t & 15;
  const int tq = t >> 4;

  float acc[4][8];
  #pragma unroll
  for (int i = 0; i < 4; ++i)
    #pragma unroll
    for (int j = 0; j < 8; ++j) acc[i][j] = 0.f;

  for (int k0 = 0; k0 < Cch; k0 += 16) {
    __syncthreads();
    {
      const int r = t >> 2, c = t & 3;
      const float4 v = *(const float4*)&A[(size_t)(m0 + r) * Cch + k0 + 4*c];
      aT[4*c + 0][r] = v.x; aT[4*c + 1][r] = v.y;
      aT[4*c + 2][r] = v.z; aT[4*c + 3][r] = v.w;
    }
    #pragma unroll
    for (int p = 0; p < 2; ++p) {
      const int id = t + 256*p;
      const int kk = id >> 5, nc = id & 31;
      const float4 v = *(const float4*)&W[(size_t)(k0 + kk) * Cch + n0 + 4*nc];
      *(float4*)&bN[kk][4*nc] = v;
    }
    __syncthreads();
    #pragma unroll
    for (int kk = 0; kk < 16; ++kk) {
      const float4 a  = *(const float4*)&aT[kk][4*tq];
      const float4 b0 = *(const float4*)&bN[kk][4*tn];
      const float4 b1 = *(const float4*)&bN[kk][64 + 4*tn];
      const float av[4] = {a.x, a.y, a.z, a.w};
      const float bw[8] = {b0.x, b0.y, b0.z, b0.w, b1.x, b1.y, b1.z, b1.w};
      #pragma unroll
      for (int qi = 0; qi < 4; ++qi)
        #pragma unroll
        for (int ni = 0; ni < 8; ++ni) acc[qi][ni] += av[qi] * bw[ni];
    }
  }

  const float4 bb0 = *(const float4*)&bias[n0 + 4*tn];
  const float4 bb1 = *(const float4*)&bias[n0 + 64 + 4*tn];
  #pragma unroll
  for (int qi = 0; qi < 4; ++qi) {
    const int m = m0 + 4*tq + qi;
    float4 o0, o1;
    o0.x = acc[qi][0] + bb0.x; o0.y = acc[qi][1] + bb0.y;
    o0.z = acc[qi][2] + bb0.z; o0.w = acc[qi][3] + bb0.w;
    o1.x = acc[qi][4] + bb1.x; o1.y = acc[qi][5] + bb1.y;
    o1.z = acc[qi][6] + bb1.z; o1.w = acc[qi][7] + bb1.w;
    *(float4*)&out[(size_t)m * Cch + n0 + 4*tn]      = o0;
    *(float4*)&out[(size_t)m * Cch + n0 + 64 + 4*tn] = o1;
  }
}

} // anonymous namespace

// ---------------------------------------------------------------------------
extern "C" void kernel_launch(void* const* d_in, const int* in_sizes, int n_in,
                              void* d_out, int out_size, void* d_ws, size_t ws_size,
                              hipStream_t stream) {
  (void)in_sizes; (void)n_in; (void)out_size; (void)ws_size;

  const float* hid  = (const float*)d_in[0];
  const float* cnt  = (const float*)d_in[1];
  const float* Wq   = (const float*)d_in[2];
  const float* bq   = (const float*)d_in[3];
  const float* Wk   = (const float*)d_in[4];
  const float* bk   = (const float*)d_in[5];
  const float* Wv   = (const float*)d_in[6];
  const float* bv   = (const float*)d_in[7];
  const float* Wo   = (const float*)d_in[8];
  const float* bo   = (const float*)d_in[9];
  const int* counter = (const int*)d_in[10];
  const int* ucb     = (const int*)d_in[11];

  float* out       = (float*)d_out;          // [B,T,C]
  float* probs     = out + BTC;              // [B,H,T,T]
  float* count_out = probs + PROBSN;         // [B,H,T,T]

  // workspace: Q | K | V | ctx, each BTC floats (needs 50.3 MB)
  float* ws  = (float*)d_ws;
  float* ctx = ws + 3*BTC;

  qkv_gemm<<<dim3(Cch/128, (Bc*Tc)/64, 3), 256, 0, stream>>>(
      hid, Wq, bq, Wk, bk, Wv, bv, ws);

  attn_ucb<<<dim3(Tc/16, Bc*Hc), 512, 0, stream>>>(
      ws, cnt, counter, ucb, probs, count_out, ctx);

  pv_gemm<<<dim3(Tc/64, Bc*Hc), 256, 0, stream>>>(
      probs, ws + 2*BTC, ctx, counter, ucb);

  out_gemm<<<dim3(Cch/128, (Bc*Tc)/64), 256, 0, stream>>>(
      ctx, Wo, bo, out);
}